// Round 1
// baseline (4524.793 us; speedup 1.0000x reference)
//
#include <hip/hip_runtime.h>

// Problem constants (from reference):
//   B=4096, F0=39, D=16, CROSS_LAYER_SIZE=(128,128), H1 = 128/2 = 64
//   x  : (4096, 39, 16)  f32
//   f0 : (39*39=1521, 128) f32   -> Wr0[i,j,m] = f0[(i*39+j)*128 + m]
//   f1 : (39*64=2496, 128) f32   -> Wr1[i,j,m] = f1[(i*64+j)*128 + m]
//   dw : (192, 1) f32, db : (1,) f32
//   out: (4096, 1) f32
//
// out[b] = sum_d [ sum_{m=64..127} relu(z0[b,m,d])*dw[m-64]
//                + sum_{m=0..127}  relu(z1[b,m,d])*dw[64+m] ] + db
// with z0 = einsum(x,x,Wr0), z1 = einsum(x, h=relu(z0)[:, :64, :], Wr1)

#define F0N 39
#define DN  16
#define H1  64

// Accumulate acc[k] += sum over i in [i0, i0+IC) of x[i,d0+k] * (sum_j W[i,j,m]*vs[j][d0+k])
// wbase = &f[(i0*JN)*128 + m]; vs = LDS j-major [JN][16]; xi_base = &xs[i0*16]
template<int IC, int JN>
__device__ __forceinline__ void cross_chunk(
    const float* __restrict__ wbase,
    const float* __restrict__ vs,
    const float* __restrict__ xi_base,
    const int d0,
    float acc[8])
{
    float tmp[IC][8];
#pragma unroll
    for (int a = 0; a < IC; ++a)
#pragma unroll
        for (int k = 0; k < 8; ++k) tmp[a][k] = 0.f;

#pragma unroll 2
    for (int j = 0; j < JN; ++j) {
        const float4 xa = *(const float4*)(vs + j * 16 + d0);
        const float4 xb = *(const float4*)(vs + j * 16 + d0 + 4);
        const float xj[8] = {xa.x, xa.y, xa.z, xa.w, xb.x, xb.y, xb.z, xb.w};
#pragma unroll
        for (int a = 0; a < IC; ++a) {
            const float wv = wbase[(a * JN + j) * 128];
#pragma unroll
            for (int k = 0; k < 8; ++k) tmp[a][k] = fmaf(wv, xj[k], tmp[a][k]);
        }
    }
#pragma unroll
    for (int a = 0; a < IC; ++a) {
        const float4 xa = *(const float4*)(xi_base + a * 16 + d0);
        const float4 xb = *(const float4*)(xi_base + a * 16 + d0 + 4);
        const float xi[8] = {xa.x, xa.y, xa.z, xa.w, xb.x, xb.y, xb.z, xb.w};
#pragma unroll
        for (int k = 0; k < 8; ++k) acc[k] = fmaf(xi[k], tmp[a][k], acc[k]);
    }
}

__global__ __launch_bounds__(256, 2)
void CIN_44530220925272_kernel(const float* __restrict__ x,
                               const float* __restrict__ f0,
                               const float* __restrict__ f1,
                               const float* __restrict__ dw,
                               const float* __restrict__ db,
                               float* __restrict__ out)
{
    __shared__ __align__(16) float xs[F0N * DN];  // x[b] staged, i-major [39][16]
    __shared__ __align__(16) float hs[H1 * DN];   // h = relu(z0)[:64], j-major [64][16]
    __shared__ float red[256];

    const int b   = blockIdx.x;
    const int tid = threadIdx.x;
    const int m   = tid & 127;          // output channel
    const int d0  = (tid >> 7) * 8;     // which half of the 16 d-lanes

    // stage x[b] (624 floats)
    for (int idx = tid; idx < F0N * DN; idx += 256)
        xs[idx] = x[b * F0N * DN + idx];
    __syncthreads();

    // ---- layer 0: z0[m,d] = sum_{i,j} x[i,d] x[j,d] W0[i,j,m] ----
    float acc0[8];
#pragma unroll
    for (int k = 0; k < 8; ++k) acc0[k] = 0.f;
    cross_chunk<8, 39>(f0 + ( 0 * 39) * 128 + m, xs, xs +  0 * 16, d0, acc0);
    cross_chunk<8, 39>(f0 + ( 8 * 39) * 128 + m, xs, xs +  8 * 16, d0, acc0);
    cross_chunk<8, 39>(f0 + (16 * 39) * 128 + m, xs, xs + 16 * 16, d0, acc0);
    cross_chunk<8, 39>(f0 + (24 * 39) * 128 + m, xs, xs + 24 * 16, d0, acc0);
    cross_chunk<7, 39>(f0 + (32 * 39) * 128 + m, xs, xs + 32 * 16, d0, acc0);

    float c = 0.f;
    if (m < H1) {
        // h = relu(z0)[:, :64, :] -> LDS for layer 1
        float4 za = make_float4(fmaxf(acc0[0], 0.f), fmaxf(acc0[1], 0.f),
                                fmaxf(acc0[2], 0.f), fmaxf(acc0[3], 0.f));
        float4 zb = make_float4(fmaxf(acc0[4], 0.f), fmaxf(acc0[5], 0.f),
                                fmaxf(acc0[6], 0.f), fmaxf(acc0[7], 0.f));
        *(float4*)(hs + m * 16 + d0)     = za;
        *(float4*)(hs + m * 16 + d0 + 4) = zb;
    } else {
        // finals[0] = relu(z0)[:, 64:, :] -> weight dw[m-64]
        float s = 0.f;
#pragma unroll
        for (int k = 0; k < 8; ++k) s += fmaxf(acc0[k], 0.f);
        c = s * dw[m - H1];
    }
    __syncthreads();

    // ---- layer 1: z1[m,d] = sum_{i<39, j<64} x[i,d] h[j,d] W1[i,j,m] ----
    float acc1[8];
#pragma unroll
    for (int k = 0; k < 8; ++k) acc1[k] = 0.f;
    cross_chunk<8, 64>(f1 + ( 0 * 64) * 128 + m, hs, xs +  0 * 16, d0, acc1);
    cross_chunk<8, 64>(f1 + ( 8 * 64) * 128 + m, hs, xs +  8 * 16, d0, acc1);
    cross_chunk<8, 64>(f1 + (16 * 64) * 128 + m, hs, xs + 16 * 16, d0, acc1);
    cross_chunk<8, 64>(f1 + (24 * 64) * 128 + m, hs, xs + 24 * 16, d0, acc1);
    cross_chunk<7, 64>(f1 + (32 * 64) * 128 + m, hs, xs + 32 * 16, d0, acc1);

    float s1 = 0.f;
#pragma unroll
    for (int k = 0; k < 8; ++k) s1 += fmaxf(acc1[k], 0.f);
    c += s1 * dw[H1 + m];   // finals[1] = relu(z1) -> weights dw[64 + m]

    // ---- block reduction over 256 threads (each thread holds its 8-d partial) ----
    red[tid] = c;
    __syncthreads();
#pragma unroll
    for (int off = 128; off > 0; off >>= 1) {
        if (tid < off) red[tid] += red[tid + off];
        __syncthreads();
    }
    if (tid == 0) out[b] = red[0] + db[0];
}

extern "C" void kernel_launch(void* const* d_in, const int* in_sizes, int n_in,
                              void* d_out, int out_size, void* d_ws, size_t ws_size,
                              hipStream_t stream)
{
    const float* x  = (const float*)d_in[0];
    const float* f0 = (const float*)d_in[1];
    const float* f1 = (const float*)d_in[2];
    const float* dw = (const float*)d_in[3];
    const float* db = (const float*)d_in[4];
    float* out = (float*)d_out;

    CIN_44530220925272_kernel<<<dim3(4096), dim3(256), 0, stream>>>(x, f0, f1, dw, db, out);
}

// Round 2
// 201.163 us; speedup vs baseline: 22.4931x; 22.4931x over previous
//
#include <hip/hip_runtime.h>
#include <hip/hip_bf16.h>

// B=4096, F0=39, D=16, L=(128,128), H1=64
// MFMA formulation: per batch b, GEMM with M=16 (d-lanes), N=128 (m), K=(i,j).
//   layer0: A0[d][(i,j)] = x[b,i,d]*x[b,j,d],  K padded to 40x40=1600 (50 chunks of 32)
//   layer1: A1[d][(i,j)] = x[b,i,d]*h[b,j,d],  K = 39*64 = 2496       (78 chunks of 32)
// Weights repacked (separate kernel, every launch) into MFMA B-frag order in d_ws:
//   dest16B[(chunk*8+nf)*64 + lane] holds B[k=chunk*32+(lane>>4)*8+t][n=nf*16+(lane&15)], t=0..7
// mfma_f32_16x16x32_bf16 layouts (verified in guide):
//   A-frag: lane holds A[m=lane&15][k=(lane>>4)*8+t]
//   B-frag: lane holds B[k=(lane>>4)*8+t][n=lane&15]
//   D:      lane holds D[row=(lane>>4)*4+r][col=lane&15]

typedef __attribute__((ext_vector_type(8))) short bf16x8;
typedef __attribute__((ext_vector_type(4))) float f32x4;

#define F0N 39
#define DN  16
#define H1  64
#define L0_CHUNKS 50   // 40*40/32
#define L1_CHUNKS 78   // 39*64/32
#define N_CHUNKS  (L0_CHUNKS + L1_CHUNKS)   // 128
#define CHUNK_BYTES 8192                     // 32*128*2
#define XS_STRIDE 44   // padded from 40: bank step 12 -> 2-way max (free)
#define HS_STRIDE 68   // padded from 64: bank step 4  -> 2-way max (free)

static __device__ __forceinline__ unsigned short f2bf(float f) {
    unsigned int u = __builtin_bit_cast(unsigned int, f);
    u = (u + 0x7FFFu + ((u >> 16) & 1u)) >> 16;   // RNE
    return (unsigned short)u;
}

// ---------------- weight repack: f32 -> bf16 MFMA B-frag order ----------------
__global__ __launch_bounds__(256)
void CIN_repack(const float* __restrict__ f0, const float* __restrict__ f1,
                unsigned short* __restrict__ ws)
{
    const int tid = blockIdx.x * 256 + threadIdx.x;       // 0..65535
    const int L0T = L0_CHUNKS * 8 * 64;                   // 25600
    const int lane = tid & 63;
    const int q = lane >> 4, cc = lane & 15;
    float v[8];
    if (tid < L0T) {
        const int nf = (tid >> 6) & 7, ch = tid >> 9;
        const int n = nf * 16 + cc;
        const int k0 = ch * 32 + q * 8;
        const int i = k0 / 40, j0 = k0 - i * 40;          // j0 in {0,8,16,24,32}, no wrap
#pragma unroll
        for (int t = 0; t < 8; ++t) {
            const int j = j0 + t;
            v[t] = (i < F0N && j < F0N) ? f0[(i * F0N + j) * 128 + n] : 0.f;
        }
    } else {
        const int u = tid - L0T;
        const int nf = (u >> 6) & 7, ch = u >> 9;
        const int n = nf * 16 + cc;
        const int k0 = ch * 32 + q * 8;
        const int i = k0 >> 6, j0 = k0 & 63;
#pragma unroll
        for (int t = 0; t < 8; ++t) v[t] = f1[(i * 64 + j0 + t) * 128 + n];
    }
    unsigned int p[4];
#pragma unroll
    for (int t = 0; t < 4; ++t)
        p[t] = (unsigned int)f2bf(v[2 * t]) | ((unsigned int)f2bf(v[2 * t + 1]) << 16);
    // dest byte offset = tid*16 for BOTH layers (L0T*16 == L0 bytes exactly)
    uint4* dst = (uint4*)ws;
    dst[tid] = make_uint4(p[0], p[1], p[2], p[3]);
}

// ---------------- main kernel: 1024 blocks x 256 thr, wave w -> b = blk*4+w ----
__global__ __launch_bounds__(256, 2)
void CIN_main(const float* __restrict__ x,
              const unsigned short* __restrict__ wsb,
              const float* __restrict__ dw,
              const float* __restrict__ db,
              float* __restrict__ out)
{
    __shared__ __align__(16) unsigned short Bsh[2][4096];     // 2 x 8KB chunk dbuf
    __shared__ __align__(16) float xsT[4][DN][XS_STRIDE];     // x[b] transposed [d][i], pad
    __shared__ __align__(16) float hsT[4][DN][HS_STRIDE];     // h      [d][j], pad
    __shared__ float dws[192];

    const int tid  = threadIdx.x;
    const int w    = tid >> 6;
    const int lane = tid & 63;
    const int lm   = lane & 15;   // M-row = d
    const int lq   = lane >> 4;
    const int b    = blockIdx.x * 4 + w;

    if (tid < 192) dws[tid] = dw[tid];

    // stage + transpose x[b] (39x16 -> [d][i]); zero the i=39 pad column
    const float* xb = x + (size_t)b * (F0N * DN);
    for (int e = lane; e < F0N * DN; e += 64)
        xsT[w][e & 15][e >> 4] = xb[e];
    if (lane < DN) xsT[w][lane][F0N] = 0.f;

    auto stage = [&](int abs_chunk) {
        const char* src = (const char*)wsb + (size_t)abs_chunk * CHUNK_BYTES;
        unsigned short* ldsb = &Bsh[abs_chunk & 1][0];
#pragma unroll
        for (int s2 = 0; s2 < 2; ++s2) {
            const int nf = w + s2 * 4;
            __builtin_amdgcn_global_load_lds(
                (const __attribute__((address_space(1))) void*)(src + nf * 1024 + lane * 16),
                (__attribute__((address_space(3))) void*)(ldsb + nf * 512),
                16, 0, 0);
        }
    };

    f32x4 acc[8];
#pragma unroll
    for (int nf = 0; nf < 8; ++nf) acc[nf] = (f32x4){0.f, 0.f, 0.f, 0.f};

    stage(0);
    __syncthreads();

    // ---------------- layer 0 K-loop ----------------
    for (int ch = 0; ch < L0_CHUNKS; ++ch) {
        stage(ch + 1);                                   // ch==49 stages L1 chunk 0
        const unsigned int k0 = ch * 32 + lq * 8;
        const unsigned int i  = k0 / 40;
        const unsigned int j0 = k0 - i * 40;
        const float  xi = xsT[w][lm][i];
        const float4 xa = *(const float4*)&xsT[w][lm][j0];
        const float4 xc = *(const float4*)&xsT[w][lm][j0 + 4];
        bf16x8 af;
        af[0] = (short)f2bf(xi * xa.x); af[1] = (short)f2bf(xi * xa.y);
        af[2] = (short)f2bf(xi * xa.z); af[3] = (short)f2bf(xi * xa.w);
        af[4] = (short)f2bf(xi * xc.x); af[5] = (short)f2bf(xi * xc.y);
        af[6] = (short)f2bf(xi * xc.z); af[7] = (short)f2bf(xi * xc.w);
        const bf16x8* Bp = (const bf16x8*)&Bsh[ch & 1][0];
#pragma unroll
        for (int nf = 0; nf < 8; ++nf)
            acc[nf] = __builtin_amdgcn_mfma_f32_16x16x32_bf16(af, Bp[nf * 64 + lane], acc[nf], 0, 0, 0);
        __syncthreads();
    }

    // ---------------- layer-0 epilogue: h -> LDS, m>=64 -> csum ----------------
    float csum = 0.f;
#pragma unroll
    for (int nf = 0; nf < 4; ++nf)
#pragma unroll
        for (int r = 0; r < 4; ++r)
            hsT[w][lq * 4 + r][nf * 16 + lm] = fmaxf(acc[nf][r], 0.f);
#pragma unroll
    for (int nf = 4; nf < 8; ++nf) {
        float s = 0.f;
#pragma unroll
        for (int r = 0; r < 4; ++r) s += fmaxf(acc[nf][r], 0.f);
        csum += s * dws[(nf - 4) * 16 + lm];
    }
#pragma unroll
    for (int nf = 0; nf < 8; ++nf) acc[nf] = (f32x4){0.f, 0.f, 0.f, 0.f};

    // ---------------- layer 1 K-loop ----------------
    for (int ch = 0; ch < L1_CHUNKS; ++ch) {
        if (ch + 1 < L1_CHUNKS) stage(L0_CHUNKS + ch + 1);
        const unsigned int k0 = ch * 32 + lq * 8;
        const unsigned int i  = k0 >> 6;
        const unsigned int j0 = k0 & 63;
        const float  xi = xsT[w][lm][i];
        const float4 ha = *(const float4*)&hsT[w][lm][j0];
        const float4 hc = *(const float4*)&hsT[w][lm][j0 + 4];
        bf16x8 af;
        af[0] = (short)f2bf(xi * ha.x); af[1] = (short)f2bf(xi * ha.y);
        af[2] = (short)f2bf(xi * ha.z); af[3] = (short)f2bf(xi * ha.w);
        af[4] = (short)f2bf(xi * hc.x); af[5] = (short)f2bf(xi * hc.y);
        af[6] = (short)f2bf(xi * hc.z); af[7] = (short)f2bf(xi * hc.w);
        const bf16x8* Bp = (const bf16x8*)&Bsh[(L0_CHUNKS + ch) & 1][0];
#pragma unroll
        for (int nf = 0; nf < 8; ++nf)
            acc[nf] = __builtin_amdgcn_mfma_f32_16x16x32_bf16(af, Bp[nf * 64 + lane], acc[nf], 0, 0, 0);
        __syncthreads();
    }

    // ---------------- layer-1 epilogue + wave reduction ----------------
#pragma unroll
    for (int nf = 0; nf < 8; ++nf) {
        float s = 0.f;
#pragma unroll
        for (int r = 0; r < 4; ++r) s += fmaxf(acc[nf][r], 0.f);
        csum += s * dws[64 + nf * 16 + lm];
    }
#pragma unroll
    for (int off = 32; off > 0; off >>= 1)
        csum += __shfl_xor(csum, off, 64);
    if (lane == 0) out[b] = csum + db[0];
}

extern "C" void kernel_launch(void* const* d_in, const int* in_sizes, int n_in,
                              void* d_out, int out_size, void* d_ws, size_t ws_size,
                              hipStream_t stream)
{
    const float* x  = (const float*)d_in[0];
    const float* f0 = (const float*)d_in[1];
    const float* f1 = (const float*)d_in[2];
    const float* dw = (const float*)d_in[3];
    const float* db = (const float*)d_in[4];
    float* out = (float*)d_out;
    unsigned short* ws = (unsigned short*)d_ws;   // needs 1 MiB

    CIN_repack<<<dim3(256), dim3(256), 0, stream>>>(f0, f1, ws);
    CIN_main<<<dim3(1024), dim3(256), 0, stream>>>(x, ws, dw, db, out);
}

// Round 4
// 129.717 us; speedup vs baseline: 34.8821x; 1.5508x over previous
//
#include <hip/hip_runtime.h>

// B=4096, F0=39, D=16, L=(128,128), H1=64
// Round-4 = round-3 structure with consistent repack/loadB layout + LDS pads.
//  - mfma_f32_32x32x16_bf16, M=32 = 2 batches x 16 d, N=128 m-channels, K=(i,j).
//  - chunk = K:32 = 2 mfma-k16; quad-side (kh,half) -> i (LDS b32), t-side -> 8 consecutive j
//    (REGISTERS xv, compile-time index).
//  - B-frags: repacked to exact frag order in d_ws, loaded global->VGPR (no LDS for B,
//    no K-loop barriers), 1-chunk software prefetch.
//  - Wave = 4 batches (2 M-tiles) x 64 cols (2 col-groups). Block = 4 waves = 8 batches,
//    waves split (batch-group g = w&1) x (col-half hh = w>>1). Grid 512.
// Layouts (verified, guide m74/m101):
//  A: lane holds A[m=lane&31][k=(lane>>5)*8+t]
//  B: lane holds B[k=(lane>>5)*8+t][n=lane&31]
//  D: lane holds D[row=(r&3)+8*(r>>2)+4*(lane>>5)][col=lane&31]
// Repack dst layout (BYTES): ch*8192 + kh*4096 + cg*1024 + lane*16 + tp*4
//  (tid bits: tp=tid&3, lane=(tid>>2)&63, cg=(tid>>8)&3, kh=(tid>>10)&1, ch=tid>>11)
//  L0 ch=ig*5+jg (ig<10,jg<5): i=ig*4+kh*2+half, j=jg*8+t, zero-pad i,j>=39.
//  L1 ch=50+jg*5+ig (jg<16,ig<5): j=jg*4+kh*2+half, i=ig*8+t, zero-pad i>=39.
// Total: 130 chunks * 8192 B = 1,064,960 B of d_ws.

typedef __attribute__((ext_vector_type(8)))  short bf16x8;
typedef __attribute__((ext_vector_type(16))) float f32x16;

static __device__ __forceinline__ unsigned short f2bf_rne(float f) {
    unsigned int u = __builtin_bit_cast(unsigned int, f);
    u = (u + 0x7FFFu + ((u >> 16) & 1u)) >> 16;
    return (unsigned short)u;
}
static __device__ __forceinline__ unsigned int pk_trunc(float a, float b) {
    unsigned int ua = __builtin_bit_cast(unsigned int, a);
    unsigned int ub = __builtin_bit_cast(unsigned int, b);
    return (ua >> 16) | (ub & 0xffff0000u);
}

// ---------------- weight repack: one dword per thread, coalesced writes ----
__global__ __launch_bounds__(256)
void CIN_repack(const float* __restrict__ f0, const float* __restrict__ f1,
                unsigned int* __restrict__ ws)
{
    const int tid  = blockIdx.x * 256 + threadIdx.x;   // 266240 total
    const int tp   = tid & 3;
    const int lane = (tid >> 2) & 63;
    const int cg   = (tid >> 8) & 3;
    const int kh   = (tid >> 10) & 1;
    const int ch   = tid >> 11;                        // 0..129
    const int half = lane >> 5;
    const int n    = cg * 32 + (lane & 31);            // 0..127
    const int t0   = tp * 2;
    float v0, v1;
    if (ch < 50) {
        const int ig = ch / 5, jg = ch - ig * 5;
        const int i = ig * 4 + kh * 2 + half;          // 0..39
        const int j = jg * 8 + t0;                     // 0..38
        const bool iok = (i < 39);
        v0 = (iok && j     < 39) ? f0[(i * 39 + j    ) * 128 + n] : 0.f;
        v1 = (iok && j + 1 < 39) ? f0[(i * 39 + j + 1) * 128 + n] : 0.f;
    } else {
        const int c1 = ch - 50;
        const int jg = c1 / 5, ig = c1 - jg * 5;
        const int j = jg * 4 + kh * 2 + half;          // 0..63
        const int i = ig * 8 + t0;                     // 0..38
        v0 = (i     < 39) ? f1[( i      * 64 + j) * 128 + n] : 0.f;
        v1 = (i + 1 < 39) ? f1[((i + 1) * 64 + j) * 128 + n] : 0.f;
    }
    ws[tid] = (unsigned int)f2bf_rne(v0) | ((unsigned int)f2bf_rne(v1) << 16);
}

// ---------------- main ----------------
static __device__ __forceinline__ bf16x8 build8(float xi, float4 a, float4 b) {
    union { unsigned int u[4]; bf16x8 v; } r;
    r.u[0] = pk_trunc(xi * a.x, xi * a.y);
    r.u[1] = pk_trunc(xi * a.z, xi * a.w);
    r.u[2] = pk_trunc(xi * b.x, xi * b.y);
    r.u[3] = pk_trunc(xi * b.z, xi * b.w);
    return r.v;
}

__global__ __launch_bounds__(256, 2)
void CIN_main(const float* __restrict__ x,
              const char* __restrict__ wsB,
              const float* __restrict__ dw,
              const float* __restrict__ db,
              float* __restrict__ out)
{
    __shared__ __align__(16) float xsTi[8][40][16];  // [bb][i][d], row 39 zeroed
    __shared__ __align__(16) float xsTd[8][16][44];  // [bb][d][j], col 39 zeroed (pad 44)
    __shared__ __align__(16) float hsT[8][64][17];   // [bb][j][d], pad 17
    __shared__ float dws[192];
    __shared__ float red[2][2][4];

    const int tid  = threadIdx.x;
    const int w    = tid >> 6;
    const int lane = tid & 63;
    const int g    = w & 1;        // batch-group (4 batches)
    const int hh   = w >> 1;       // col-half (n 0..63 / 64..127)
    const int half = lane >> 5;
    const int d    = lane & 15;
    const int bsel = (lane >> 4) & 1;
    const int g4   = g * 4;

    // ---- stage x for 8 batches: 1248 float4 ----
    const float4* xg4 = (const float4*)(x + (size_t)blockIdx.x * 8 * 624);
    for (int e4 = tid; e4 < 1248; e4 += 256) {
        float4 v = xg4[e4];
        int bb = e4 / 156, r = e4 - bb * 156;
        int i = r >> 2, d0 = (r & 3) * 4;
        *(float4*)&xsTi[bb][i][d0] = v;
        xsTd[bb][d0 + 0][i] = v.x; xsTd[bb][d0 + 1][i] = v.y;
        xsTd[bb][d0 + 2][i] = v.z; xsTd[bb][d0 + 3][i] = v.w;
    }
    if (tid < 128) { int bb = tid >> 4, dd = tid & 15; xsTi[bb][39][dd] = 0.f; xsTd[bb][dd][39] = 0.f; }
    if (tid < 192) dws[tid] = dw[tid];
    __syncthreads();

    // ---- xv: lane's own-batch x row, f32, registers (40 values, idx 39 == 0) ----
    float4 xv[2][10];
#pragma unroll
    for (int p = 0; p < 2; ++p) {
        const float* src = &xsTd[g4 + p * 2 + bsel][d][0];
#pragma unroll
        for (int q = 0; q < 10; ++q) xv[p][q] = *(const float4*)(src + q * 4);
    }

    const char* wlane = wsB + lane * 16;
    bf16x8 Bc[2][2], Bn[2][2];
    auto loadB = [&](int ch, bf16x8 (&B)[2][2]) {
        const char* base = wlane + (size_t)ch * 8192;
#pragma unroll
        for (int kh = 0; kh < 2; ++kh)
#pragma unroll
            for (int c = 0; c < 2; ++c)
                B[kh][c] = *(const bf16x8*)(base + kh * 4096 + (hh * 2 + c) * 1024);
    };

    f32x16 acc[2][2];
#pragma unroll
    for (int p = 0; p < 2; ++p)
#pragma unroll
        for (int c = 0; c < 2; ++c)
#pragma unroll
            for (int r = 0; r < 16; ++r) acc[p][c][r] = 0.f;

    loadB(0, Bc);

    // ---------------- layer 0: 50 chunks ----------------
    for (int ig = 0; ig < 10; ++ig) {
        float xiv[2][2];
#pragma unroll
        for (int p = 0; p < 2; ++p)
#pragma unroll
            for (int kh = 0; kh < 2; ++kh)
                xiv[p][kh] = xsTi[g4 + p * 2 + bsel][ig * 4 + kh * 2 + half][d];
#pragma unroll
        for (int jg = 0; jg < 5; ++jg) {
            const int ch = ig * 5 + jg;
            loadB(ch + 1, Bn);          // ch=49 -> chunk 50 (L1 chunk 0, reused after barrier)
            bf16x8 A[2][2];
#pragma unroll
            for (int p = 0; p < 2; ++p)
#pragma unroll
                for (int kh = 0; kh < 2; ++kh)
                    A[p][kh] = build8(xiv[p][kh], xv[p][jg * 2], xv[p][jg * 2 + 1]);
#pragma unroll
            for (int p = 0; p < 2; ++p)
#pragma unroll
                for (int c = 0; c < 2; ++c) {
                    acc[p][c] = __builtin_amdgcn_mfma_f32_32x32x16_bf16(A[p][0], Bc[0][c], acc[p][c], 0, 0, 0);
                    acc[p][c] = __builtin_amdgcn_mfma_f32_32x32x16_bf16(A[p][1], Bc[1][c], acc[p][c], 0, 0, 0);
                }
#pragma unroll
            for (int kh = 0; kh < 2; ++kh)
#pragma unroll
                for (int c = 0; c < 2; ++c) Bc[kh][c] = Bn[kh][c];
        }
    }

    // ---------------- layer-0 epilogue ----------------
    float cs[4] = {0.f, 0.f, 0.f, 0.f};
    if (hh == 0) {
#pragma unroll
        for (int p = 0; p < 2; ++p)
#pragma unroll
            for (int c = 0; c < 2; ++c)
#pragma unroll
                for (int r = 0; r < 16; ++r) {
                    const int row = (r & 3) + 8 * (r >> 2) + 4 * half;
                    hsT[g4 + p * 2 + (row >> 4)][c * 32 + (lane & 31)][row & 15] =
                        fmaxf(acc[p][c][r], 0.f);
                }
    } else {
#pragma unroll
        for (int p = 0; p < 2; ++p)
#pragma unroll
            for (int c = 0; c < 2; ++c) {
                const float dwv = dws[c * 32 + (lane & 31)];   // dw[n-64]
#pragma unroll
                for (int r = 0; r < 16; ++r) {
                    const int row = (r & 3) + 8 * (r >> 2) + 4 * half;
                    cs[p * 2 + (row >> 4)] += fmaxf(acc[p][c][r], 0.f) * dwv;
                }
            }
    }
#pragma unroll
    for (int p = 0; p < 2; ++p)
#pragma unroll
        for (int c = 0; c < 2; ++c)
#pragma unroll
            for (int r = 0; r < 16; ++r) acc[p][c][r] = 0.f;
    __syncthreads();

    // ---------------- layer 1: 80 chunks (Bc already holds chunk 50) ----------------
    for (int jg = 0; jg < 16; ++jg) {
        float hjv[2][2];
#pragma unroll
        for (int p = 0; p < 2; ++p)
#pragma unroll
            for (int kh = 0; kh < 2; ++kh)
                hjv[p][kh] = hsT[g4 + p * 2 + bsel][jg * 4 + kh * 2 + half][d];
#pragma unroll
        for (int ig2 = 0; ig2 < 5; ++ig2) {
            const int ch = 50 + jg * 5 + ig2;
            const int chn = (ch < 129) ? ch + 1 : 129;
            loadB(chn, Bn);
            bf16x8 A[2][2];
#pragma unroll
            for (int p = 0; p < 2; ++p)
#pragma unroll
                for (int kh = 0; kh < 2; ++kh)
                    A[p][kh] = build8(hjv[p][kh], xv[p][ig2 * 2], xv[p][ig2 * 2 + 1]);
#pragma unroll
            for (int p = 0; p < 2; ++p)
#pragma unroll
                for (int c = 0; c < 2; ++c) {
                    acc[p][c] = __builtin_amdgcn_mfma_f32_32x32x16_bf16(A[p][0], Bc[0][c], acc[p][c], 0, 0, 0);
                    acc[p][c] = __builtin_amdgcn_mfma_f32_32x32x16_bf16(A[p][1], Bc[1][c], acc[p][c], 0, 0, 0);
                }
#pragma unroll
            for (int kh = 0; kh < 2; ++kh)
#pragma unroll
                for (int c = 0; c < 2; ++c) Bc[kh][c] = Bn[kh][c];
        }
    }

    // ---------------- layer-1 epilogue + reduction ----------------
#pragma unroll
    for (int p = 0; p < 2; ++p)
#pragma unroll
        for (int c = 0; c < 2; ++c) {
            const float dwv = dws[64 + (2 * hh + c) * 32 + (lane & 31)];
#pragma unroll
            for (int r = 0; r < 16; ++r) {
                const int row = (r & 3) + 8 * (r >> 2) + 4 * half;
                cs[p * 2 + (row >> 4)] += fmaxf(acc[p][c][r], 0.f) * dwv;
            }
        }
#pragma unroll
    for (int rr = 0; rr < 4; ++rr)
#pragma unroll
        for (int off = 32; off > 0; off >>= 1)
            cs[rr] += __shfl_xor(cs[rr], off, 64);
    if (lane == 0) {
#pragma unroll
        for (int rr = 0; rr < 4; ++rr) red[g][hh][rr] = cs[rr];
    }
    __syncthreads();
    if (tid < 8) {
        const int g2 = tid >> 2, rr = tid & 3;
        out[blockIdx.x * 8 + g2 * 4 + rr] = red[g2][0][rr] + red[g2][1][rr] + db[0];
    }
}

extern "C" void kernel_launch(void* const* d_in, const int* in_sizes, int n_in,
                              void* d_out, int out_size, void* d_ws, size_t ws_size,
                              hipStream_t stream)
{
    const float* x  = (const float*)d_in[0];
    const float* f0 = (const float*)d_in[1];
    const float* f1 = (const float*)d_in[2];
    const float* dw = (const float*)d_in[3];
    const float* db = (const float*)d_in[4];
    float* out = (float*)d_out;

    CIN_repack<<<dim3(1040), dim3(256), 0, stream>>>(f0, f1, (unsigned int*)d_ws);
    CIN_main<<<dim3(512), dim3(256), 0, stream>>>(x, (const char*)d_ws, dw, db, out);
}